// Round 11
// baseline (649.670 us; speedup 1.0000x reference)
//
#include <hip/hip_runtime.h>
#include <hip/hip_fp16.h>
#include <math.h>

#define NN 50000
#define NE 1600000
#define KORD 5
#define NB 196          // ceil(NN/256)
#define QTR 12500       // node quarter (k_deg)
#define GE 782          // epi grid: ceil(NN/64)
#define MT 64           // epi node tile
#define NBK 1563        // ceil(NN/32) destination buckets (32 nodes each)
#define NBP 1600        // padded bucket stride
#define NCH 128         // chunks for bucket kernels
#define ECH (NE / NCH)  // 12500
#define EC4 (NE / 64)   // 25000 (k_deg chunks)

#define SCALE_W 2097152.0f          // 2^21 spmm fixed point
#define INV_SCALE_W (1.0f / 2097152.0f)
#define SCALE_D 4194304.0f          // 2^22 degree fixed point
#define INV_SCALE_D (1.0f / 4194304.0f)

// ---------------- deg: LDS int-fixed-point weighted row histogram ----------
__global__ __launch_bounds__(1024) void k_deg(const int* __restrict__ ei,
                                              const float* __restrict__ ew,
                                              int* __restrict__ deg_g) {
    __shared__ int h[QTR];   // 50 KB
    int q = blockIdx.x >> 6, ch = blockIdx.x & 63;
    for (int i = threadIdx.x; i < QTR; i += 1024) h[i] = 0;
    __syncthreads();
    int base = ch * EC4, lo = q * QTR;
    for (int e = base + threadIdx.x; e < base + EC4; e += 1024) {
        int li = ei[e] - lo;
        if ((unsigned)li < (unsigned)QTR)
            atomicAdd(&h[li], __float2int_rn(ew[e] * SCALE_D));  // ds_add_u32
    }
    __syncthreads();
    int* outp = deg_g + blockIdx.x * QTR;
    for (int i = threadIdx.x; i < QTR; i += 1024) outp[i] = h[i];
}

__global__ __launch_bounds__(256) void k_dis2(const int* __restrict__ deg_g,
                                              float* __restrict__ dis) {
    int n = blockIdx.x * 256 + threadIdx.x;
    if (n >= NN) return;
    int q = n / QTR, i = n % QTR;
    const int* p = deg_g + (q * 64) * QTR + i;
    int s = 0;
#pragma unroll
    for (int c = 0; c < 64; c++) s += p[c * QTR];
    float d = (float)s * INV_SCALE_D;
    dis[n] = s > 0 ? rsqrtf(fmaxf(d, 1e-30f)) : 0.f;
}

// ---------------- bucket histogram: bh[ch][b] ----------
__global__ __launch_bounds__(1024) void k_bhist(const int* __restrict__ ei,
                                                int* __restrict__ bh) {
    __shared__ int hist[NBK];
    int ch = blockIdx.x;
    for (int i = threadIdx.x; i < NBK; i += 1024) hist[i] = 0;
    __syncthreads();
    const int* cols = ei + NE;
    int base = ch * ECH;
    for (int e = base + threadIdx.x; e < base + ECH; e += 1024)
        atomicAdd(&hist[cols[e] >> 5], 1);
    __syncthreads();
    int* outp = bh + ch * NBP;
    for (int b = threadIdx.x; b < NBK; b += 1024) outp[b] = hist[b];
}

__global__ __launch_bounds__(256) void k_btot(const int* __restrict__ bh,
                                              int* __restrict__ tot) {
    int b = blockIdx.x * 256 + threadIdx.x;
    if (b >= NBP) return;
    int s = 0;
    if (b < NBK) {
#pragma unroll 8
        for (int ch = 0; ch < NCH; ch++) s += bh[ch * NBP + b];
    }
    tot[b] = s;
}

// one block: pair-compressed exclusive scan of 1563 totals -> off_bk
__global__ __launch_bounds__(1024) void k_bscan1(const int* __restrict__ tot,
                                                 int* __restrict__ off_bk) {
    __shared__ int s[1024];
    int t = threadIdx.x;
    int a0 = (2 * t < NBP) ? tot[2 * t] : 0;
    int a1 = (2 * t + 1 < NBP) ? tot[2 * t + 1] : 0;
    s[t] = a0 + a1;
    __syncthreads();
    for (int d = 1; d < 1024; d <<= 1) {
        int u = (t >= d) ? s[t - d] : 0;
        __syncthreads();
        s[t] += u;
        __syncthreads();
    }
    int excl = (t == 0) ? 0 : s[t - 1];
    if (2 * t < NBK) off_bk[2 * t] = excl;
    if (2 * t + 1 < NBK) off_bk[2 * t + 1] = excl + a0;
    if (t == 0) off_bk[NBK] = NE;
}

__global__ __launch_bounds__(256) void k_bcur(int* __restrict__ bh,
                                              const int* __restrict__ off_bk) {
    int b = blockIdx.x * 256 + threadIdx.x;
    if (b >= NBK) return;
    int run = off_bk[b];
    for (int ch = 0; ch < NCH; ch++) {
        int v = bh[ch * NBP + b];
        bh[ch * NBP + b] = run;
        run += v;
    }
}

// coarse permute: record = (r | local_c<<16, weight-bits)
__global__ __launch_bounds__(1024) void k_cperm(const int* __restrict__ ei,
                                                const float* __restrict__ ew,
                                                const float* __restrict__ dis,
                                                const int* __restrict__ bh,
                                                int2* __restrict__ edges) {
    __shared__ int cur[NBK];
    int ch = blockIdx.x;
    const int* cp = bh + ch * NBP;
    for (int b = threadIdx.x; b < NBK; b += 1024) cur[b] = cp[b];
    __syncthreads();
    int base = ch * ECH;
    for (int e = base + threadIdx.x; e < base + ECH; e += 1024) {
        int r = ei[e], c = ei[NE + e];
        float w = -dis[r] * ew[e] * dis[c];
        int pos = atomicAdd(&cur[c >> 5], 1);   // ds_add_u32, native
        int packed = (int)((unsigned)r | ((unsigned)(c & 31) << 16));
        edges[pos] = make_int2(packed, __float_as_int(w));
    }
}

// ---------------- per-bucket exact counting sort by local dest ----------
__global__ __launch_bounds__(256) void k_sort(const int* __restrict__ off_bk,
                                              const int2* __restrict__ edges,
                                              int2* __restrict__ edges2) {
    __shared__ int cnt[32];
    __shared__ int cur[32];
    int b = blockIdx.x;
    int e0 = off_bk[b], e1 = off_bk[b + 1];
    if (threadIdx.x < 32) cnt[threadIdx.x] = 0;
    __syncthreads();
    for (int i = e0 + threadIdx.x; i < e1; i += 256)
        atomicAdd(&cnt[edges[i].x >> 16], 1);
    __syncthreads();
    if (threadIdx.x == 0) {
        int run = e0;
#pragma unroll
        for (int k = 0; k < 32; k++) { cur[k] = run; run += cnt[k]; }
    }
    __syncthreads();
    for (int i = e0 + threadIdx.x; i < e1; i += 256) {
        int2 e = edges[i];
        int p = atomicAdd(&cur[e.x >> 16], 1);
        edges2[p] = e;
    }
}

// ---------------- spmm: feature-half pass (16 features), sorted strips ------
// 64 strips x 4 subs; per half-pass the gather working set is one 64-B line
// per source row (3.2 MB) -> fits each XCD's 4 MiB L2.
#define SPMM_FLUSH(CC)                                         \
    {                                                          \
        int* A = &acc[CC][sub * 4];                            \
        atomicAdd(A + 0, __float2int_rn(ax * SCALE_W));        \
        atomicAdd(A + 1, __float2int_rn(ay * SCALE_W));        \
        atomicAdd(A + 2, __float2int_rn(az * SCALE_W));        \
        atomicAdd(A + 3, __float2int_rn(aw * SCALE_W));        \
        ax = 0.f; ay = 0.f; az = 0.f; aw = 0.f;                \
    }

__global__ __launch_bounds__(256) void k_spmm(const int* __restrict__ off_bk,
                                              const int2* __restrict__ edges,
                                              const float* __restrict__ vin,
                                              const float* __restrict__ prev,
                                              float* __restrict__ vout,
                                              float scale, int fq0) {
    __shared__ int acc[32][17];
    int b = blockIdx.x;
    for (int i = threadIdx.x; i < 32 * 17; i += 256) (&acc[0][0])[i] = 0;
    __syncthreads();
    int e0 = off_bk[b], e1 = off_bk[b + 1];
    int len = e1 - e0;
    int g = threadIdx.x >> 2, sub = threadIdx.x & 3;
    int fq = fq0 + sub;
    int S = (len + 63) >> 6;
    int i = e0 + g * S;
    int iE = i + S; if (iE > e1) iE = e1;
    const float4* vin4 = (const float4*)vin;
    if (i < iE) {
        int curc = edges[i].x >> 16;
        float ax = 0.f, ay = 0.f, az = 0.f, aw = 0.f;
        for (; i + 4 <= iE; i += 4) {
            int2 ea = edges[i];
            int2 eb = edges[i + 1];
            int2 ec = edges[i + 2];
            int2 ed = edges[i + 3];
            float4 va = vin4[(ea.x & 0xffff) * 8 + fq];   // 4 independent
            float4 vb = vin4[(eb.x & 0xffff) * 8 + fq];   // gather chains
            float4 vc = vin4[(ec.x & 0xffff) * 8 + fq];
            float4 vd = vin4[(ed.x & 0xffff) * 8 + fq];
            int c;
            float w;
            c = ea.x >> 16; if (c != curc) { SPMM_FLUSH(curc); curc = c; }
            w = __int_as_float(ea.y);
            ax = fmaf(w, va.x, ax); ay = fmaf(w, va.y, ay);
            az = fmaf(w, va.z, az); aw = fmaf(w, va.w, aw);
            c = eb.x >> 16; if (c != curc) { SPMM_FLUSH(curc); curc = c; }
            w = __int_as_float(eb.y);
            ax = fmaf(w, vb.x, ax); ay = fmaf(w, vb.y, ay);
            az = fmaf(w, vb.z, az); aw = fmaf(w, vb.w, aw);
            c = ec.x >> 16; if (c != curc) { SPMM_FLUSH(curc); curc = c; }
            w = __int_as_float(ec.y);
            ax = fmaf(w, vc.x, ax); ay = fmaf(w, vc.y, ay);
            az = fmaf(w, vc.z, az); aw = fmaf(w, vc.w, aw);
            c = ed.x >> 16; if (c != curc) { SPMM_FLUSH(curc); curc = c; }
            w = __int_as_float(ed.y);
            ax = fmaf(w, vd.x, ax); ay = fmaf(w, vd.y, ay);
            az = fmaf(w, vd.z, az); aw = fmaf(w, vd.w, aw);
        }
        for (; i < iE; i++) {
            int2 e = edges[i];
            float4 v = vin4[(e.x & 0xffff) * 8 + fq];
            int c = e.x >> 16;
            if (c != curc) { SPMM_FLUSH(curc); curc = c; }
            float w = __int_as_float(e.y);
            ax = fmaf(w, v.x, ax); ay = fmaf(w, v.y, ay);
            az = fmaf(w, v.z, az); aw = fmaf(w, v.w, aw);
        }
        SPMM_FLUSH(curc);
    }
    __syncthreads();
    if (threadIdx.x < 128) {
        float sf = scale * INV_SCALE_W;
        int base = b << 5;
        int nl = threadIdx.x >> 2, s = threadIdx.x & 3;
        int n = base + nl;
        if (n < NN) {
            const int* a = &acc[nl][s * 4];
            int fi = n * 8 + fq0 + s;
            float4 o;
            if (prev) {
                float4 p = ((const float4*)prev)[fi];
                o = make_float4(fmaf(sf, (float)a[0], -p.x),
                                fmaf(sf, (float)a[1], -p.y),
                                fmaf(sf, (float)a[2], -p.z),
                                fmaf(sf, (float)a[3], -p.w));
            } else {
                o = make_float4(sf * (float)a[0], sf * (float)a[1],
                                sf * (float)a[2], sf * (float)a[3]);
            }
            ((float4*)vout)[fi] = o;
        }
    }
}

// ---------------- epi1a: gate-split LDS GEMM partial (z or h pre-act) -------
// grid (GE, 2): blockIdx.y = gate (0=z, 1=h). Disjoint outputs -> plain store.
__global__ __launch_bounds__(256) void k_epi1a(
    const float* __restrict__ x, const float* __restrict__ t1,
    const float* __restrict__ t2, const float* __restrict__ t3,
    const float* __restrict__ t4, const float* __restrict__ Wx1,
    float* __restrict__ zp, float* __restrict__ hp) {
    __shared__ __half T[5][MT][36];
    int n0 = blockIdx.x * MT;
    int gate = blockIdx.y;
    const float* bufs[5] = {x, t1, t2, t3, t4};
#pragma unroll
    for (int b = 0; b < 5; b++) {
        for (int idx = threadIdx.x; idx < MT * 8; idx += 256) {
            int r = idx >> 3, c4 = idx & 7;
            int rr = n0 + r; if (rr >= NN) rr = NN - 1;
            float4 v = *(const float4*)(bufs[b] + rr * 32 + c4 * 4);
            __half2* dst = (__half2*)&T[b][r][c4 * 4];
            dst[0] = __floats2half2_rn(v.x, v.y);
            dst[1] = __floats2half2_rn(v.z, v.w);
        }
    }
    __syncthreads();
    int nq = threadIdx.x & 15, oq = threadIdx.x >> 4;
    int ob = oq * 2;
    const float* W = Wx1 + gate * 2 * (KORD * 32 * 32);  // gate0->Wz, gate1->Wh
    float a_[4][2] = {{0.f}};
#pragma unroll
    for (int b = 0; b < 5; b++) {
#pragma unroll 4
        for (int i = 0; i < 32; i++) {
            int kw = b * 1024 + i * 32 + ob;
            float w0 = W[kw], w1 = W[kw + 1];
#pragma unroll
            for (int a = 0; a < 4; a++) {
                float tx = __half2float(T[b][nq + 16 * a][i]);
                a_[a][0] = fmaf(tx, w0, a_[a][0]);
                a_[a][1] = fmaf(tx, w1, a_[a][1]);
            }
        }
    }
    float* o = gate ? hp : zp;
#pragma unroll
    for (int a = 0; a < 4; a++) {
        int n = n0 + nq + 16 * a;
        if (n < NN) {
            o[n * 32 + ob] = a_[a][0];
            o[n * 32 + ob + 1] = a_[a][1];
        }
    }
}

// epi1b: elementwise gate combine -> hb
__global__ __launch_bounds__(256) void k_epi1b(
    const float* __restrict__ zp, const float* __restrict__ hp,
    const float* __restrict__ bx1, const float* __restrict__ bh1,
    float* __restrict__ h) {
    int idx = blockIdx.x * 256 + threadIdx.x;
    if (idx >= NN * 32) return;
    int j = idx & 31;
    float zz = zp[idx] + bx1[j] + bh1[j];
    float hh = hp[idx] + bx1[64 + j] + bh1[64 + j];
    float z = 1.f / (1.f + __expf(-zz));
    float tt = __expf(-2.f * fabsf(hh));
    float ht = copysignf((1.f - tt) / (1.f + tt), hh);
    h[idx] = fmaxf((1.f - z) * ht, 0.f);
}

// ---------------- epi2a: gate-split partial (z or h pre-act, 16 cols) -------
__global__ __launch_bounds__(256) void k_epi2a(
    const float* __restrict__ hin, const float* __restrict__ t1,
    const float* __restrict__ t2, const float* __restrict__ t3,
    const float* __restrict__ t4, const float* __restrict__ Wx2,
    float* __restrict__ zp, float* __restrict__ hp) {
    __shared__ __half T[5][MT][36];
    int n0 = blockIdx.x * MT;
    int gate = blockIdx.y;
    const float* bufs[5] = {hin, t1, t2, t3, t4};
#pragma unroll
    for (int b = 0; b < 5; b++) {
        for (int idx = threadIdx.x; idx < MT * 8; idx += 256) {
            int r = idx >> 3, c4 = idx & 7;
            int rr = n0 + r; if (rr >= NN) rr = NN - 1;
            float4 v = *(const float4*)(bufs[b] + rr * 32 + c4 * 4);
            __half2* dst = (__half2*)&T[b][r][c4 * 4];
            dst[0] = __floats2half2_rn(v.x, v.y);
            dst[1] = __floats2half2_rn(v.z, v.w);
        }
    }
    __syncthreads();
    int nq = threadIdx.x & 15, j = threadIdx.x >> 4;
    const float* W = Wx2 + gate * 2 * (KORD * 32 * 16);
    float a_[4] = {0.f};
#pragma unroll
    for (int b = 0; b < 5; b++) {
#pragma unroll 4
        for (int i = 0; i < 32; i++) {
            float w0 = W[b * 512 + i * 16 + j];
#pragma unroll
            for (int a = 0; a < 4; a++) {
                float tx = __half2float(T[b][nq + 16 * a][i]);
                a_[a] = fmaf(tx, w0, a_[a]);
            }
        }
    }
    float* o = gate ? hp : zp;
#pragma unroll
    for (int a = 0; a < 4; a++) {
        int n = n0 + nq + 16 * a;
        if (n < NN) o[n * 16 + j] = a_[a];
    }
}

// epi2b: gates + fused final linear (node per thread, LDS-staged partials)
__global__ __launch_bounds__(256) void k_epi2b(
    const float* __restrict__ zp, const float* __restrict__ hp,
    const float* __restrict__ bx2, const float* __restrict__ bh2,
    const float* __restrict__ Wl, const float* __restrict__ bl,
    float* __restrict__ out) {
    __shared__ float Z[256][17];
    __shared__ float H[256][17];
    int n0 = blockIdx.x * 256;
    for (int idx = threadIdx.x; idx < 256 * 4; idx += 256) {
        int r = idx >> 2, c = idx & 3;
        int rr = n0 + r; if (rr >= NN) rr = NN - 1;
        float4 z4 = ((const float4*)(zp + rr * 16))[c];
        float4 h4 = ((const float4*)(hp + rr * 16))[c];
        float* zd = &Z[r][c * 4];
        float* hd = &H[r][c * 4];
        zd[0] = z4.x; zd[1] = z4.y; zd[2] = z4.z; zd[3] = z4.w;
        hd[0] = h4.x; hd[1] = h4.y; hd[2] = h4.z; hd[3] = h4.w;
    }
    __syncthreads();
    int t = threadIdx.x;
    int n = n0 + t;
    if (n >= NN) return;
    float h2[16];
#pragma unroll
    for (int j = 0; j < 16; j++) {
        float zz = Z[t][j] + bx2[j] + bh2[j];
        float hh = H[t][j] + bx2[32 + j] + bh2[32 + j];
        float z = 1.f / (1.f + __expf(-zz));
        float tt = __expf(-2.f * fabsf(hh));
        float ht = copysignf((1.f - tt) / (1.f + tt), hh);
        h2[j] = fmaxf((1.f - z) * ht, 0.f);
    }
#pragma unroll
    for (int p = 0; p < 12; p++) {
        float o = bl[p];
#pragma unroll
        for (int jj = 0; jj < 16; jj++) o = fmaf(h2[jj], Wl[p * 16 + jj], o);
        out[n * 12 + p] = o;
    }
}

// ---------------- launch ----------------

extern "C" void kernel_launch(void* const* d_in, const int* in_sizes, int n_in,
                              void* d_out, int out_size, void* d_ws, size_t ws_size,
                              hipStream_t stream) {
    const float* x   = (const float*)d_in[0];
    const int*   ei  = (const int*)d_in[1];
    const float* ew  = (const float*)d_in[2];
    const float* Wx1 = (const float*)d_in[3];
    const float* bx1 = (const float*)d_in[4];
    const float* bh1 = (const float*)d_in[6];
    const float* Wx2 = (const float*)d_in[7];
    const float* bx2 = (const float*)d_in[8];
    const float* bh2 = (const float*)d_in[10];
    const float* Wl  = (const float*)d_in[11];
    const float* bl  = (const float*)d_in[12];
    float* out = (float*)d_out;

    float* ws     = (float*)d_ws;
    float* dis    = ws;                         // 50048 floats
    int*   bh     = (int*)(ws + 50048);         // NCH*NBP ints
    int*   tot    = bh + NCH * NBP;             // NBP ints
    int*   off_bk = tot + NBP;                  // NBP ints
    int2*  edges  = (int2*)(off_bk + NBP);      // NE int2 (coarse)
    int2*  edges2 = edges + NE;                 // NE int2 (exact-sorted)
    float* T1     = (float*)(edges2 + NE);      // NN*32 floats each
    float* T2     = T1 + NN * 32;
    float* T3     = T2 + NN * 32;
    float* T4     = T3 + NN * 32;
    float* hb     = T4 + NN * 32;
    int*   deg_g  = (int*)T1;   // T1+T2 region, dead before spmm writes
    float* zp     = (float*)edges;              // alias: edges dead after sort
    float* hp     = zp + NN * 32;
    float* zp2    = zp;                         // cell-2 partials (N*16 each)
    float* hp2    = zp + NN * 16;

    k_deg  <<<256, 1024, 0, stream>>>(ei, ew, deg_g);
    k_dis2 <<<NB, 256, 0, stream>>>(deg_g, dis);
    k_bhist<<<NCH, 1024, 0, stream>>>(ei, bh);
    k_btot <<<7, 256, 0, stream>>>(bh, tot);
    k_bscan1<<<1, 1024, 0, stream>>>(tot, off_bk);
    k_bcur <<<7, 256, 0, stream>>>(bh, off_bk);
    k_cperm<<<NCH, 1024, 0, stream>>>(ei, ew, dis, bh, edges);
    k_sort <<<NBK, 256, 0, stream>>>(off_bk, edges, edges2);

    // ---- cell 1: v = x; per feature-half the full Chebyshev chain ----
    for (int h = 0; h < 2; h++) {
        int fq0 = h * 4;
        k_spmm<<<NBK, 256, 0, stream>>>(off_bk, edges2, x,  nullptr, T1, 1.f, fq0);
        k_spmm<<<NBK, 256, 0, stream>>>(off_bk, edges2, T1, x,       T2, 2.f, fq0);
        k_spmm<<<NBK, 256, 0, stream>>>(off_bk, edges2, T2, T1,      T3, 2.f, fq0);
        k_spmm<<<NBK, 256, 0, stream>>>(off_bk, edges2, T3, T2,      T4, 2.f, fq0);
    }
    k_epi1a<<<dim3(GE, 2), 256, 0, stream>>>(x, T1, T2, T3, T4, Wx1, zp, hp);
    k_epi1b<<<(NN * 32) / 256, 256, 0, stream>>>(zp, hp, bx1, bh1, hb);

    // ---- cell 2: v = hb ----
    for (int h = 0; h < 2; h++) {
        int fq0 = h * 4;
        k_spmm<<<NBK, 256, 0, stream>>>(off_bk, edges2, hb, nullptr, T1, 1.f, fq0);
        k_spmm<<<NBK, 256, 0, stream>>>(off_bk, edges2, T1, hb,      T2, 2.f, fq0);
        k_spmm<<<NBK, 256, 0, stream>>>(off_bk, edges2, T2, T1,      T3, 2.f, fq0);
        k_spmm<<<NBK, 256, 0, stream>>>(off_bk, edges2, T3, T2,      T4, 2.f, fq0);
    }
    k_epi2a<<<dim3(GE, 2), 256, 0, stream>>>(hb, T1, T2, T3, T4, Wx2, zp2, hp2);
    k_epi2b<<<196, 256, 0, stream>>>(zp2, hp2, bx2, bh2, Wl, bl, out);
}

// Round 12
// 426.977 us; speedup vs baseline: 1.5216x; 1.5216x over previous
//
#include <hip/hip_runtime.h>
#include <math.h>

#define NN 50000
#define NE 1600000
#define KORD 5
#define NB 196          // ceil(NN/256)
#define QTR 12500       // node quarter (k_deg)
#define GE 782          // epi grid: ceil(NN/64)
#define MT 64           // epi node tile
#define NBK 1563        // ceil(NN/32) destination buckets (32 nodes each)
#define NBP 1600        // padded bucket stride
#define NCH 128         // chunks for bucket kernels
#define ECH (NE / NCH)  // 12500
#define EC4 (NE / 64)   // 25000 (k_deg chunks)
#define PADE 1800192    // edge buffer capacity (NE + NBK*128, rounded)

#define SCALE_W 2097152.0f          // 2^21 spmm fixed point
#define INV_SCALE_W (1.0f / 2097152.0f)
#define SCALE_D 4194304.0f          // 2^22 degree fixed point
#define INV_SCALE_D (1.0f / 4194304.0f)

// ---------------- deg: LDS int-fixed-point weighted row histogram ----------
__global__ __launch_bounds__(1024) void k_deg(const int* __restrict__ ei,
                                              const float* __restrict__ ew,
                                              int* __restrict__ deg_g) {
    __shared__ int h[QTR];   // 50 KB
    int q = blockIdx.x >> 6, ch = blockIdx.x & 63;
    for (int i = threadIdx.x; i < QTR; i += 1024) h[i] = 0;
    __syncthreads();
    int base = ch * EC4, lo = q * QTR;
    for (int e = base + threadIdx.x; e < base + EC4; e += 1024) {
        int li = ei[e] - lo;
        if ((unsigned)li < (unsigned)QTR)
            atomicAdd(&h[li], __float2int_rn(ew[e] * SCALE_D));  // ds_add_u32
    }
    __syncthreads();
    int* outp = deg_g + blockIdx.x * QTR;
    for (int i = threadIdx.x; i < QTR; i += 1024) outp[i] = h[i];
}

__global__ __launch_bounds__(256) void k_dis2(const int* __restrict__ deg_g,
                                              float* __restrict__ dis) {
    int n = blockIdx.x * 256 + threadIdx.x;
    if (n >= NN) return;
    int q = n / QTR, i = n % QTR;
    const int* p = deg_g + (q * 64) * QTR + i;
    int s = 0;
#pragma unroll
    for (int c = 0; c < 64; c++) s += p[c * QTR];
    float d = (float)s * INV_SCALE_D;
    dis[n] = s > 0 ? rsqrtf(fmaxf(d, 1e-30f)) : 0.f;
}

// ---------------- bucket histogram: bh[ch][b] ----------
__global__ __launch_bounds__(1024) void k_bhist(const int* __restrict__ ei,
                                                int* __restrict__ bh) {
    __shared__ int hist[NBK];
    int ch = blockIdx.x;
    for (int i = threadIdx.x; i < NBK; i += 1024) hist[i] = 0;
    __syncthreads();
    const int* cols = ei + NE;
    int base = ch * ECH;
    for (int e = base + threadIdx.x; e < base + ECH; e += 1024)
        atomicAdd(&hist[cols[e] >> 5], 1);
    __syncthreads();
    int* outp = bh + ch * NBP;
    for (int b = threadIdx.x; b < NBK; b += 1024) outp[b] = hist[b];
}

__global__ __launch_bounds__(256) void k_btot(const int* __restrict__ bh,
                                              int* __restrict__ tot) {
    int b = blockIdx.x * 256 + threadIdx.x;
    if (b >= NBP) return;
    int s = 0;
    if (b < NBK) {
#pragma unroll 8
        for (int ch = 0; ch < NCH; ch++) s += bh[ch * NBP + b];
    }
    tot[b] = s;
}

// one block: pair-compressed exclusive scan of PADDED totals -> off_bk
// each bucket's extent rounded up to a multiple of 128 (tail-free spmm loop)
__global__ __launch_bounds__(1024) void k_bscan1(const int* __restrict__ tot,
                                                 int* __restrict__ off_bk) {
    __shared__ int s[1024];
    int t = threadIdx.x;
    int a0 = (2 * t < NBP) ? tot[2 * t] : 0;
    int a1 = (2 * t + 1 < NBP) ? tot[2 * t + 1] : 0;
    int p0 = (a0 + 127) & ~127;
    int p1 = (a1 + 127) & ~127;
    s[t] = p0 + p1;
    __syncthreads();
    for (int d = 1; d < 1024; d <<= 1) {
        int u = (t >= d) ? s[t - d] : 0;
        __syncthreads();
        s[t] += u;
        __syncthreads();
    }
    int excl = (t == 0) ? 0 : s[t - 1];
    if (2 * t < NBK) off_bk[2 * t] = excl;
    if (2 * t + 1 < NBK) off_bk[2 * t + 1] = excl + p0;
    if (t == 1023) off_bk[NBK] = s[1023];
}

__global__ __launch_bounds__(256) void k_bcur(int* __restrict__ bh,
                                              const int* __restrict__ off_bk) {
    int b = blockIdx.x * 256 + threadIdx.x;
    if (b >= NBK) return;
    int run = off_bk[b];
    for (int ch = 0; ch < NCH; ch++) {
        int v = bh[ch * NBP + b];
        bh[ch * NBP + b] = run;
        run += v;
    }
}

// fill pad region of each bucket with zero-weight sentinel edges
__global__ __launch_bounds__(128) void k_pad(const int* __restrict__ off_bk,
                                             const int* __restrict__ tot,
                                             int2* __restrict__ edges) {
    int b = blockIdx.x;
    int start = off_bk[b] + tot[b];
    int end = off_bk[b + 1];
    for (int i = start + threadIdx.x; i < end; i += 128)
        edges[i] = make_int2(0, 0);   // r=0, c_local=0, w=0.0f
}

// coarse permute: record = (r | local_c<<16, weight-bits)
__global__ __launch_bounds__(1024) void k_cperm(const int* __restrict__ ei,
                                                const float* __restrict__ ew,
                                                const float* __restrict__ dis,
                                                const int* __restrict__ bh,
                                                int2* __restrict__ edges) {
    __shared__ int cur[NBK];
    int ch = blockIdx.x;
    const int* cp = bh + ch * NBP;
    for (int b = threadIdx.x; b < NBK; b += 1024) cur[b] = cp[b];
    __syncthreads();
    int base = ch * ECH;
    for (int e = base + threadIdx.x; e < base + ECH; e += 1024) {
        int r = ei[e], c = ei[NE + e];
        float w = -dis[r] * ew[e] * dis[c];
        int pos = atomicAdd(&cur[c >> 5], 1);   // ds_add_u32, native
        int packed = (int)((unsigned)r | ((unsigned)(c & 31) << 16));
        edges[pos] = make_int2(packed, __float_as_int(w));
    }
}

// ---------------- spmm: 32-node buckets, software-pipelined edge loads ------
// 8 lanes/edge (float4); 4 gather chains; next batch's edge records are
// prefetched before the current batch's gathers -> edge-load latency hidden.
// Bucket extents are multiples of 128 -> uniform tail-free loop.
__global__ __launch_bounds__(256) void k_spmm(const int* __restrict__ off_bk,
                                              const int2* __restrict__ edges,
                                              const float* __restrict__ vin,
                                              const float* __restrict__ prev,
                                              float* __restrict__ vout,
                                              float scale) {
    __shared__ int acc[32][33];
    int b = blockIdx.x;
    for (int i = threadIdx.x; i < 32 * 33; i += 256) (&acc[0][0])[i] = 0;
    __syncthreads();
    int e0 = off_bk[b], e1 = off_bk[b + 1];
    int group = threadIdx.x >> 3, sub = threadIdx.x & 7;
    const float4* vin4 = (const float4*)vin;
    int i = e0 + group;
    if (i < e1) {
        int2 ea = edges[i];
        int2 eb = edges[i + 32];
        int2 ec = edges[i + 64];
        int2 ed = edges[i + 96];
        while (true) {
            int ni = i + 128;
            bool more = ni < e1;
            int2 na, nb, nc, nd;
            if (more) {                        // prefetch next batch
                na = edges[ni];
                nb = edges[ni + 32];
                nc = edges[ni + 64];
                nd = edges[ni + 96];
            }
            unsigned ra = (unsigned)ea.x, rb = (unsigned)eb.x;
            unsigned rc = (unsigned)ec.x, rd = (unsigned)ed.x;
            float4 va = vin4[(ra & 0xffffu) * 8 + sub];   // 4 independent
            float4 vb = vin4[(rb & 0xffffu) * 8 + sub];   // gather chains
            float4 vc = vin4[(rc & 0xffffu) * 8 + sub];
            float4 vd = vin4[(rd & 0xffffu) * 8 + sub];
            float wa = __int_as_float(ea.y) * SCALE_W;
            float wb = __int_as_float(eb.y) * SCALE_W;
            float wc = __int_as_float(ec.y) * SCALE_W;
            float wd = __int_as_float(ed.y) * SCALE_W;
            int* aa = &acc[ra >> 16][sub * 4];
            int* ab = &acc[rb >> 16][sub * 4];
            int* ac = &acc[rc >> 16][sub * 4];
            int* ad = &acc[rd >> 16][sub * 4];
            atomicAdd(aa + 0, __float2int_rn(wa * va.x));
            atomicAdd(aa + 1, __float2int_rn(wa * va.y));
            atomicAdd(aa + 2, __float2int_rn(wa * va.z));
            atomicAdd(aa + 3, __float2int_rn(wa * va.w));
            atomicAdd(ab + 0, __float2int_rn(wb * vb.x));
            atomicAdd(ab + 1, __float2int_rn(wb * vb.y));
            atomicAdd(ab + 2, __float2int_rn(wb * vb.z));
            atomicAdd(ab + 3, __float2int_rn(wb * vb.w));
            atomicAdd(ac + 0, __float2int_rn(wc * vc.x));
            atomicAdd(ac + 1, __float2int_rn(wc * vc.y));
            atomicAdd(ac + 2, __float2int_rn(wc * vc.z));
            atomicAdd(ac + 3, __float2int_rn(wc * vc.w));
            atomicAdd(ad + 0, __float2int_rn(wd * vd.x));
            atomicAdd(ad + 1, __float2int_rn(wd * vd.y));
            atomicAdd(ad + 2, __float2int_rn(wd * vd.z));
            atomicAdd(ad + 3, __float2int_rn(wd * vd.w));
            if (!more) break;
            i = ni; ea = na; eb = nb; ec = nc; ed = nd;
        }
    }
    __syncthreads();
    float sf = scale * INV_SCALE_W;
    int base = b << 5;
    int nl = threadIdx.x >> 3, s4 = threadIdx.x & 7;
    int n = base + nl;
    if (n < NN) {
        const int* a = &acc[nl][s4 * 4];
        float4 o;
        if (prev) {
            float4 p = ((const float4*)prev)[n * 8 + s4];
            o = make_float4(fmaf(sf, (float)a[0], -p.x),
                            fmaf(sf, (float)a[1], -p.y),
                            fmaf(sf, (float)a[2], -p.z),
                            fmaf(sf, (float)a[3], -p.w));
        } else {
            o = make_float4(sf * (float)a[0], sf * (float)a[1],
                            sf * (float)a[2], sf * (float)a[3]);
        }
        ((float4*)vout)[n * 8 + s4] = o;
    }
}

// ---------------- epi1: LDS-tiled GEMM (K=160 -> 32z+32h) + GRU fuse --------
// thread = (nq in 16, oq in 16): 4 nodes (stride 16) x 2 z-cols + 2 h-cols.
__global__ __launch_bounds__(256) void k_epi1(
    const float* __restrict__ x, const float* __restrict__ t1,
    const float* __restrict__ t2, const float* __restrict__ t3,
    const float* __restrict__ t4, const float* __restrict__ Wx1,
    const float* __restrict__ bx1, const float* __restrict__ bh1,
    float* __restrict__ h) {
    __shared__ float T[5][MT][33];
    int n0 = blockIdx.x * MT;
    const float* bufs[5] = {x, t1, t2, t3, t4};
#pragma unroll
    for (int b = 0; b < 5; b++) {
        for (int idx = threadIdx.x; idx < MT * 8; idx += 256) {
            int r = idx >> 3, c4 = idx & 7;
            int rr = n0 + r; if (rr >= NN) rr = NN - 1;
            float4 v = *(const float4*)(bufs[b] + rr * 32 + c4 * 4);
            float* dst = &T[b][r][c4 * 4];
            dst[0] = v.x; dst[1] = v.y; dst[2] = v.z; dst[3] = v.w;
        }
    }
    __syncthreads();
    int nq = threadIdx.x & 15, oq = threadIdx.x >> 4;
    int ob = oq * 2;
    const float* Wz = Wx1;
    const float* Wh = Wx1 + 2 * KORD * 32 * 32;
    float az_[4][2] = {{0.f}}, ah_[4][2] = {{0.f}};
#pragma unroll
    for (int b = 0; b < 5; b++) {
#pragma unroll 4
        for (int i = 0; i < 32; i++) {
            int kw = b * 1024 + i * 32 + ob;
            float wz0 = Wz[kw], wz1 = Wz[kw + 1];
            float wh0 = Wh[kw], wh1 = Wh[kw + 1];
#pragma unroll
            for (int a = 0; a < 4; a++) {
                float tx = T[b][nq + 16 * a][i];
                az_[a][0] = fmaf(tx, wz0, az_[a][0]);
                az_[a][1] = fmaf(tx, wz1, az_[a][1]);
                ah_[a][0] = fmaf(tx, wh0, ah_[a][0]);
                ah_[a][1] = fmaf(tx, wh1, ah_[a][1]);
            }
        }
    }
#pragma unroll
    for (int a = 0; a < 4; a++) {
        int n = n0 + nq + 16 * a;
        if (n < NN) {
#pragma unroll
            for (int c = 0; c < 2; c++) {
                int j = ob + c;
                float zz = az_[a][c] + bx1[j] + bh1[j];
                float hh = ah_[a][c] + bx1[64 + j] + bh1[64 + j];
                float z = 1.f / (1.f + __expf(-zz));
                float tt = __expf(-2.f * fabsf(hh));
                float ht = copysignf((1.f - tt) / (1.f + tt), hh);
                h[n * 32 + j] = fmaxf((1.f - z) * ht, 0.f);
            }
        }
    }
}

// ---------------- epi2: LDS-tiled GEMM (K=160 -> 16z+16h) + final linear ----
__global__ __launch_bounds__(256) void k_epi2(
    const float* __restrict__ hin, const float* __restrict__ t1,
    const float* __restrict__ t2, const float* __restrict__ t3,
    const float* __restrict__ t4, const float* __restrict__ Wx2,
    const float* __restrict__ bx2, const float* __restrict__ bh2,
    const float* __restrict__ Wl, const float* __restrict__ bl,
    float* __restrict__ out) {
    __shared__ float T[5][MT][33];
    __shared__ float H2[MT][17];
    int n0 = blockIdx.x * MT;
    const float* bufs[5] = {hin, t1, t2, t3, t4};
#pragma unroll
    for (int b = 0; b < 5; b++) {
        for (int idx = threadIdx.x; idx < MT * 8; idx += 256) {
            int r = idx >> 3, c4 = idx & 7;
            int rr = n0 + r; if (rr >= NN) rr = NN - 1;
            float4 v = *(const float4*)(bufs[b] + rr * 32 + c4 * 4);
            float* dst = &T[b][r][c4 * 4];
            dst[0] = v.x; dst[1] = v.y; dst[2] = v.z; dst[3] = v.w;
        }
    }
    __syncthreads();
    int nq = threadIdx.x & 15, j = threadIdx.x >> 4;
    const float* Wz = Wx2;
    const float* Wh = Wx2 + 2 * KORD * 32 * 16;
    float az_[4] = {0.f}, ah_[4] = {0.f};
#pragma unroll
    for (int b = 0; b < 5; b++) {
#pragma unroll 4
        for (int i = 0; i < 32; i++) {
            int kw = b * 512 + i * 16 + j;
            float wz0 = Wz[kw], wh0 = Wh[kw];
#pragma unroll
            for (int a = 0; a < 4; a++) {
                float tx = T[b][nq + 16 * a][i];
                az_[a] = fmaf(tx, wz0, az_[a]);
                ah_[a] = fmaf(tx, wh0, ah_[a]);
            }
        }
    }
#pragma unroll
    for (int a = 0; a < 4; a++) {
        float zz = az_[a] + bx2[j] + bh2[j];
        float hh = ah_[a] + bx2[32 + j] + bh2[32 + j];
        float z = 1.f / (1.f + __expf(-zz));
        float tt = __expf(-2.f * fabsf(hh));
        float ht = copysignf((1.f - tt) / (1.f + tt), hh);
        H2[nq + 16 * a][j] = fmaxf((1.f - z) * ht, 0.f);
    }
    __syncthreads();
    for (int idx = threadIdx.x; idx < MT * 12; idx += 256) {
        int n = idx / 12, p = idx % 12;
        int gn = n0 + n;
        if (gn < NN) {
            float o = bl[p];
#pragma unroll
            for (int jj = 0; jj < 16; jj++) o = fmaf(H2[n][jj], Wl[p * 16 + jj], o);
            out[gn * 12 + p] = o;
        }
    }
}

// ---------------- launch ----------------

extern "C" void kernel_launch(void* const* d_in, const int* in_sizes, int n_in,
                              void* d_out, int out_size, void* d_ws, size_t ws_size,
                              hipStream_t stream) {
    const float* x   = (const float*)d_in[0];
    const int*   ei  = (const int*)d_in[1];
    const float* ew  = (const float*)d_in[2];
    const float* Wx1 = (const float*)d_in[3];
    const float* bx1 = (const float*)d_in[4];
    const float* bh1 = (const float*)d_in[6];
    const float* Wx2 = (const float*)d_in[7];
    const float* bx2 = (const float*)d_in[8];
    const float* bh2 = (const float*)d_in[10];
    const float* Wl  = (const float*)d_in[11];
    const float* bl  = (const float*)d_in[12];
    float* out = (float*)d_out;

    float* ws     = (float*)d_ws;
    float* dis    = ws;                         // 50048 floats
    int*   bh     = (int*)(ws + 50048);         // NCH*NBP ints
    int*   tot    = bh + NCH * NBP;             // NBP ints
    int*   off_bk = tot + NBP;                  // NBP ints
    int2*  edges  = (int2*)(off_bk + NBP);      // PADE int2 (padded buckets)
    float* T1     = (float*)(edges + PADE);     // NN*32 floats each
    float* T2     = T1 + NN * 32;
    float* T3     = T2 + NN * 32;
    float* T4     = T3 + NN * 32;
    float* hb     = T4 + NN * 32;
    int*   deg_g  = (int*)T1;  // 256*QTR ints (T1+T2 region, dead before spmm)

    k_deg  <<<256, 1024, 0, stream>>>(ei, ew, deg_g);
    k_dis2 <<<NB, 256, 0, stream>>>(deg_g, dis);
    k_bhist<<<NCH, 1024, 0, stream>>>(ei, bh);
    k_btot <<<7, 256, 0, stream>>>(bh, tot);
    k_bscan1<<<1, 1024, 0, stream>>>(tot, off_bk);
    k_bcur <<<7, 256, 0, stream>>>(bh, off_bk);
    k_pad  <<<NBK, 128, 0, stream>>>(off_bk, tot, edges);
    k_cperm<<<NCH, 1024, 0, stream>>>(ei, ew, dis, bh, edges);

    // ---- cell 1: v = x ----
    k_spmm<<<NBK, 256, 0, stream>>>(off_bk, edges, x,  nullptr, T1, 1.f);
    k_spmm<<<NBK, 256, 0, stream>>>(off_bk, edges, T1, x,       T2, 2.f);
    k_spmm<<<NBK, 256, 0, stream>>>(off_bk, edges, T2, T1,      T3, 2.f);
    k_spmm<<<NBK, 256, 0, stream>>>(off_bk, edges, T3, T2,      T4, 2.f);
    k_epi1<<<GE, 256, 0, stream>>>(x, T1, T2, T3, T4, Wx1, bx1, bh1, hb);

    // ---- cell 2: v = hb ----
    k_spmm<<<NBK, 256, 0, stream>>>(off_bk, edges, hb, nullptr, T1, 1.f);
    k_spmm<<<NBK, 256, 0, stream>>>(off_bk, edges, T1, hb,      T2, 2.f);
    k_spmm<<<NBK, 256, 0, stream>>>(off_bk, edges, T2, T1,      T3, 2.f);
    k_spmm<<<NBK, 256, 0, stream>>>(off_bk, edges, T3, T2,      T4, 2.f);
    k_epi2<<<GE, 256, 0, stream>>>(hb, T1, T2, T3, T4, Wx2, bx2, bh2, Wl, bl, out);
}

// Round 13
// 376.400 us; speedup vs baseline: 1.7260x; 1.1344x over previous
//
#include <hip/hip_runtime.h>
#include <math.h>

#define NN 50000
#define NE 1600000
#define KORD 5
#define NB 196          // ceil(NN/256)
#define QTR 12500       // node quarter (k_deg)
#define GE 782          // epi grid: ceil(NN/64)
#define MT 64           // epi node tile
#define NBK 1563        // ceil(NN/32) destination buckets (32 nodes each)
#define NBP 1600        // padded bucket stride
#define NCH 128         // chunks for bucket kernels
#define ECH (NE / NCH)  // 12500
#define EC4 (NE / 64)   // 25000 (k_deg chunks)
#define PADE 1800192    // edge buffer capacity (NE + NBK*128, rounded)

#define SCALE_W 2097152.0f          // 2^21 spmm fixed point
#define INV_SCALE_W (1.0f / 2097152.0f)
#define SCALE_D 4194304.0f          // 2^22 degree fixed point
#define INV_SCALE_D (1.0f / 4194304.0f)

typedef _Float16 half8 __attribute__((ext_vector_type(8)));
typedef _Float16 half4v __attribute__((ext_vector_type(4)));
typedef float float4v __attribute__((ext_vector_type(4)));

// ---------------- deg: LDS int-fixed-point weighted row histogram ----------
__global__ __launch_bounds__(1024) void k_deg(const int* __restrict__ ei,
                                              const float* __restrict__ ew,
                                              int* __restrict__ deg_g) {
    __shared__ int h[QTR];   // 50 KB
    int q = blockIdx.x >> 6, ch = blockIdx.x & 63;
    for (int i = threadIdx.x; i < QTR; i += 1024) h[i] = 0;
    __syncthreads();
    int base = ch * EC4, lo = q * QTR;
    for (int e = base + threadIdx.x; e < base + EC4; e += 1024) {
        int li = ei[e] - lo;
        if ((unsigned)li < (unsigned)QTR)
            atomicAdd(&h[li], __float2int_rn(ew[e] * SCALE_D));  // ds_add_u32
    }
    __syncthreads();
    int* outp = deg_g + blockIdx.x * QTR;
    for (int i = threadIdx.x; i < QTR; i += 1024) outp[i] = h[i];
}

__global__ __launch_bounds__(256) void k_dis2(const int* __restrict__ deg_g,
                                              float* __restrict__ dis) {
    int n = blockIdx.x * 256 + threadIdx.x;
    if (n >= NN) return;
    int q = n / QTR, i = n % QTR;
    const int* p = deg_g + (q * 64) * QTR + i;
    int s = 0;
#pragma unroll
    for (int c = 0; c < 64; c++) s += p[c * QTR];
    float d = (float)s * INV_SCALE_D;
    dis[n] = s > 0 ? rsqrtf(fmaxf(d, 1e-30f)) : 0.f;
}

// ---------------- bucket histogram: bh[ch][b] ----------
__global__ __launch_bounds__(1024) void k_bhist(const int* __restrict__ ei,
                                                int* __restrict__ bh) {
    __shared__ int hist[NBK];
    int ch = blockIdx.x;
    for (int i = threadIdx.x; i < NBK; i += 1024) hist[i] = 0;
    __syncthreads();
    const int* cols = ei + NE;
    int base = ch * ECH;
    for (int e = base + threadIdx.x; e < base + ECH; e += 1024)
        atomicAdd(&hist[cols[e] >> 5], 1);
    __syncthreads();
    int* outp = bh + ch * NBP;
    for (int b = threadIdx.x; b < NBK; b += 1024) outp[b] = hist[b];
}

__global__ __launch_bounds__(256) void k_btot(const int* __restrict__ bh,
                                              int* __restrict__ tot) {
    int b = blockIdx.x * 256 + threadIdx.x;
    if (b >= NBP) return;
    int s = 0;
    if (b < NBK) {
#pragma unroll 8
        for (int ch = 0; ch < NCH; ch++) s += bh[ch * NBP + b];
    }
    tot[b] = s;
}

// one block: pair-compressed exclusive scan of PADDED totals -> off_bk
__global__ __launch_bounds__(1024) void k_bscan1(const int* __restrict__ tot,
                                                 int* __restrict__ off_bk) {
    __shared__ int s[1024];
    int t = threadIdx.x;
    int a0 = (2 * t < NBP) ? tot[2 * t] : 0;
    int a1 = (2 * t + 1 < NBP) ? tot[2 * t + 1] : 0;
    int p0 = (a0 + 127) & ~127;
    int p1 = (a1 + 127) & ~127;
    s[t] = p0 + p1;
    __syncthreads();
    for (int d = 1; d < 1024; d <<= 1) {
        int u = (t >= d) ? s[t - d] : 0;
        __syncthreads();
        s[t] += u;
        __syncthreads();
    }
    int excl = (t == 0) ? 0 : s[t - 1];
    if (2 * t < NBK) off_bk[2 * t] = excl;
    if (2 * t + 1 < NBK) off_bk[2 * t + 1] = excl + p0;
    if (t == 1023) off_bk[NBK] = s[1023];
}

__global__ __launch_bounds__(256) void k_bcur(int* __restrict__ bh,
                                              const int* __restrict__ off_bk) {
    int b = blockIdx.x * 256 + threadIdx.x;
    if (b >= NBK) return;
    int run = off_bk[b];
    for (int ch = 0; ch < NCH; ch++) {
        int v = bh[ch * NBP + b];
        bh[ch * NBP + b] = run;
        run += v;
    }
}

// fill pad region of each bucket with zero-weight sentinel edges
__global__ __launch_bounds__(128) void k_pad(const int* __restrict__ off_bk,
                                             const int* __restrict__ tot,
                                             int2* __restrict__ edges) {
    int b = blockIdx.x;
    int start = off_bk[b] + tot[b];
    int end = off_bk[b + 1];
    for (int i = start + threadIdx.x; i < end; i += 128)
        edges[i] = make_int2(0, 0);   // r=0, c_local=0, w=0.0f
}

// coarse permute: record = (r | local_c<<16, weight-bits)
__global__ __launch_bounds__(1024) void k_cperm(const int* __restrict__ ei,
                                                const float* __restrict__ ew,
                                                const float* __restrict__ dis,
                                                const int* __restrict__ bh,
                                                int2* __restrict__ edges) {
    __shared__ int cur[NBK];
    int ch = blockIdx.x;
    const int* cp = bh + ch * NBP;
    for (int b = threadIdx.x; b < NBK; b += 1024) cur[b] = cp[b];
    __syncthreads();
    int base = ch * ECH;
    for (int e = base + threadIdx.x; e < base + ECH; e += 1024) {
        int r = ei[e], c = ei[NE + e];
        float w = -dis[r] * ew[e] * dis[c];
        int pos = atomicAdd(&cur[c >> 5], 1);   // ds_add_u32, native
        int packed = (int)((unsigned)r | ((unsigned)(c & 31) << 16));
        edges[pos] = make_int2(packed, __float_as_int(w));
    }
}

// ---------------- spmm: 32-node buckets, software-pipelined edge loads ------
__global__ __launch_bounds__(256) void k_spmm(const int* __restrict__ off_bk,
                                              const int2* __restrict__ edges,
                                              const float* __restrict__ vin,
                                              const float* __restrict__ prev,
                                              float* __restrict__ vout,
                                              float scale) {
    __shared__ int acc[32][33];
    int b = blockIdx.x;
    for (int i = threadIdx.x; i < 32 * 33; i += 256) (&acc[0][0])[i] = 0;
    __syncthreads();
    int e0 = off_bk[b], e1 = off_bk[b + 1];
    int group = threadIdx.x >> 3, sub = threadIdx.x & 7;
    const float4* vin4 = (const float4*)vin;
    int i = e0 + group;
    if (i < e1) {
        int2 ea = edges[i];
        int2 eb = edges[i + 32];
        int2 ec = edges[i + 64];
        int2 ed = edges[i + 96];
        while (true) {
            int ni = i + 128;
            bool more = ni < e1;
            int2 na, nb, nc, nd;
            if (more) {                        // prefetch next batch
                na = edges[ni];
                nb = edges[ni + 32];
                nc = edges[ni + 64];
                nd = edges[ni + 96];
            }
            unsigned ra = (unsigned)ea.x, rb = (unsigned)eb.x;
            unsigned rc = (unsigned)ec.x, rd = (unsigned)ed.x;
            float4 va = vin4[(ra & 0xffffu) * 8 + sub];   // 4 independent
            float4 vb = vin4[(rb & 0xffffu) * 8 + sub];   // gather chains
            float4 vc = vin4[(rc & 0xffffu) * 8 + sub];
            float4 vd = vin4[(rd & 0xffffu) * 8 + sub];
            float wa = __int_as_float(ea.y) * SCALE_W;
            float wb = __int_as_float(eb.y) * SCALE_W;
            float wc = __int_as_float(ec.y) * SCALE_W;
            float wd = __int_as_float(ed.y) * SCALE_W;
            int* aa = &acc[ra >> 16][sub * 4];
            int* ab = &acc[rb >> 16][sub * 4];
            int* ac = &acc[rc >> 16][sub * 4];
            int* ad = &acc[rd >> 16][sub * 4];
            atomicAdd(aa + 0, __float2int_rn(wa * va.x));
            atomicAdd(aa + 1, __float2int_rn(wa * va.y));
            atomicAdd(aa + 2, __float2int_rn(wa * va.z));
            atomicAdd(aa + 3, __float2int_rn(wa * va.w));
            atomicAdd(ab + 0, __float2int_rn(wb * vb.x));
            atomicAdd(ab + 1, __float2int_rn(wb * vb.y));
            atomicAdd(ab + 2, __float2int_rn(wb * vb.z));
            atomicAdd(ab + 3, __float2int_rn(wb * vb.w));
            atomicAdd(ac + 0, __float2int_rn(wc * vc.x));
            atomicAdd(ac + 1, __float2int_rn(wc * vc.y));
            atomicAdd(ac + 2, __float2int_rn(wc * vc.z));
            atomicAdd(ac + 3, __float2int_rn(wc * vc.w));
            atomicAdd(ad + 0, __float2int_rn(wd * vd.x));
            atomicAdd(ad + 1, __float2int_rn(wd * vd.y));
            atomicAdd(ad + 2, __float2int_rn(wd * vd.z));
            atomicAdd(ad + 3, __float2int_rn(wd * vd.w));
            if (!more) break;
            i = ni; ea = na; eb = nb; ec = nc; ed = nd;
        }
    }
    __syncthreads();
    float sf = scale * INV_SCALE_W;
    int base = b << 5;
    int nl = threadIdx.x >> 3, s4 = threadIdx.x & 7;
    int n = base + nl;
    if (n < NN) {
        const int* a = &acc[nl][s4 * 4];
        float4 o;
        if (prev) {
            float4 p = ((const float4*)prev)[n * 8 + s4];
            o = make_float4(fmaf(sf, (float)a[0], -p.x),
                            fmaf(sf, (float)a[1], -p.y),
                            fmaf(sf, (float)a[2], -p.z),
                            fmaf(sf, (float)a[3], -p.w));
        } else {
            o = make_float4(sf * (float)a[0], sf * (float)a[1],
                            sf * (float)a[2], sf * (float)a[3]);
        }
        ((float4*)vout)[n * 8 + s4] = o;
    }
}

// ---------------- epi1: MFMA GEMM (64 nodes x 64 outs x K=160) + GRU --------
// wave w = node tile 16w. A-frag: T fp16 LDS, A[m=lane&15][k=quad*8+j].
// B-frag: Wt fp16 LDS transposed, B[k=quad*8+j][n=lane&15].
// C/D: col=lane&15, row=quad*4+reg. z-tile t and h-tile t+2 share lane/reg.
__global__ __launch_bounds__(256) void k_epi1(
    const float* __restrict__ x, const float* __restrict__ t1,
    const float* __restrict__ t2, const float* __restrict__ t3,
    const float* __restrict__ t4, const float* __restrict__ Wx1,
    const float* __restrict__ bx1, const float* __restrict__ bh1,
    float* __restrict__ h) {
    __shared__ _Float16 T[5][MT][40];   // 25.6 KB, stride 80 B (16B-aligned frags)
    __shared__ _Float16 Wt[64][168];    // 21.5 KB, [n][k], stride 336 B
    int n0 = blockIdx.x * MT;
    const float* bufs[5] = {x, t1, t2, t3, t4};
#pragma unroll
    for (int b = 0; b < 5; b++) {
        for (int idx = threadIdx.x; idx < MT * 8; idx += 256) {
            int r = idx >> 3, c4 = idx & 7;
            int rr = n0 + r; if (rr >= NN) rr = NN - 1;
            float4 v = *(const float4*)(bufs[b] + rr * 32 + c4 * 4);
            *(half4v*)&T[b][r][c4 * 4] =
                (half4v){(_Float16)v.x, (_Float16)v.y, (_Float16)v.z, (_Float16)v.w};
        }
    }
    const float* Wz = Wx1;
    const float* Wh = Wx1 + 2 * KORD * 32 * 32;
    for (int idx = threadIdx.x; idx < 160 * 64; idx += 256) {
        int k = idx >> 6, n = idx & 63;          // coalesced in n
        int b = k >> 5, i = k & 31;
        float w = (n < 32) ? Wz[b * 1024 + i * 32 + n]
                           : Wh[b * 1024 + i * 32 + (n - 32)];
        Wt[n][k] = (_Float16)w;
    }
    __syncthreads();
    int wave = threadIdx.x >> 6;
    int lane = threadIdx.x & 63;
    int lo = lane & 15, quad = lane >> 4;
    float4v acc[4];
#pragma unroll
    for (int t = 0; t < 4; t++) acc[t] = (float4v){0.f, 0.f, 0.f, 0.f};
#pragma unroll
    for (int b = 0; b < 5; b++) {
        half8 a = *(half8*)&T[b][wave * 16 + lo][quad * 8];
#pragma unroll
        for (int t = 0; t < 4; t++) {
            half8 bf = *(half8*)&Wt[t * 16 + lo][b * 32 + quad * 8];
            acc[t] = __builtin_amdgcn_mfma_f32_16x16x32_f16(a, bf, acc[t], 0, 0, 0);
        }
    }
    int nd_base = n0 + wave * 16 + quad * 4;
#pragma unroll
    for (int t = 0; t < 2; t++) {
        int j = t * 16 + lo;
        float bz = bx1[j] + bh1[j];
        float bhb = bx1[64 + j] + bh1[64 + j];
#pragma unroll
        for (int reg = 0; reg < 4; reg++) {
            int nd = nd_base + reg;
            if (nd < NN) {
                float zz = acc[t][reg] + bz;
                float hh = acc[t + 2][reg] + bhb;
                float z = 1.f / (1.f + __expf(-zz));
                float tt = __expf(-2.f * fabsf(hh));
                float ht = copysignf((1.f - tt) / (1.f + tt), hh);
                h[nd * 32 + j] = fmaxf((1.f - z) * ht, 0.f);
            }
        }
    }
}

// ---------------- epi2: MFMA GEMM (64 x 32 x 160) + GRU + final linear ------
__global__ __launch_bounds__(256) void k_epi2(
    const float* __restrict__ hin, const float* __restrict__ t1,
    const float* __restrict__ t2, const float* __restrict__ t3,
    const float* __restrict__ t4, const float* __restrict__ Wx2,
    const float* __restrict__ bx2, const float* __restrict__ bh2,
    const float* __restrict__ Wl, const float* __restrict__ bl,
    float* __restrict__ out) {
    __shared__ _Float16 T[5][MT][40];   // 25.6 KB
    __shared__ _Float16 Wt[32][168];    // 10.8 KB, [n][k]: n<16 z, n>=16 h
    __shared__ float H2[MT][17];
    int n0 = blockIdx.x * MT;
    const float* bufs[5] = {hin, t1, t2, t3, t4};
#pragma unroll
    for (int b = 0; b < 5; b++) {
        for (int idx = threadIdx.x; idx < MT * 8; idx += 256) {
            int r = idx >> 3, c4 = idx & 7;
            int rr = n0 + r; if (rr >= NN) rr = NN - 1;
            float4 v = *(const float4*)(bufs[b] + rr * 32 + c4 * 4);
            *(half4v*)&T[b][r][c4 * 4] =
                (half4v){(_Float16)v.x, (_Float16)v.y, (_Float16)v.z, (_Float16)v.w};
        }
    }
    const float* Wz = Wx2;
    const float* Wh = Wx2 + 2 * KORD * 32 * 16;
    for (int idx = threadIdx.x; idx < 160 * 32; idx += 256) {
        int k = idx >> 5, n = idx & 31;
        int b = k >> 5, i = k & 31;
        float w = (n < 16) ? Wz[b * 512 + i * 16 + n]
                           : Wh[b * 512 + i * 16 + (n - 16)];
        Wt[n][k] = (_Float16)w;
    }
    __syncthreads();
    int wave = threadIdx.x >> 6;
    int lane = threadIdx.x & 63;
    int lo = lane & 15, quad = lane >> 4;
    float4v acc[2];
    acc[0] = (float4v){0.f, 0.f, 0.f, 0.f};
    acc[1] = (float4v){0.f, 0.f, 0.f, 0.f};
#pragma unroll
    for (int b = 0; b < 5; b++) {
        half8 a = *(half8*)&T[b][wave * 16 + lo][quad * 8];
#pragma unroll
        for (int t = 0; t < 2; t++) {
            half8 bf = *(half8*)&Wt[t * 16 + lo][b * 32 + quad * 8];
            acc[t] = __builtin_amdgcn_mfma_f32_16x16x32_f16(a, bf, acc[t], 0, 0, 0);
        }
    }
    {
        int j = lo;
        float bz = bx2[j] + bh2[j];
        float bhb = bx2[32 + j] + bh2[32 + j];
        int ndl_base = wave * 16 + quad * 4;
#pragma unroll
        for (int reg = 0; reg < 4; reg++) {
            float zz = acc[0][reg] + bz;
            float hh = acc[1][reg] + bhb;
            float z = 1.f / (1.f + __expf(-zz));
            float tt = __expf(-2.f * fabsf(hh));
            float ht = copysignf((1.f - tt) / (1.f + tt), hh);
            H2[ndl_base + reg][j] = fmaxf((1.f - z) * ht, 0.f);
        }
    }
    __syncthreads();
    for (int idx = threadIdx.x; idx < MT * 12; idx += 256) {
        int n = idx / 12, p = idx % 12;
        int gn = n0 + n;
        if (gn < NN) {
            float o = bl[p];
#pragma unroll
            for (int jj = 0; jj < 16; jj++) o = fmaf(H2[n][jj], Wl[p * 16 + jj], o);
            out[gn * 12 + p] = o;
        }
    }
}

// ---------------- launch ----------------

extern "C" void kernel_launch(void* const* d_in, const int* in_sizes, int n_in,
                              void* d_out, int out_size, void* d_ws, size_t ws_size,
                              hipStream_t stream) {
    const float* x   = (const float*)d_in[0];
    const int*   ei  = (const int*)d_in[1];
    const float* ew  = (const float*)d_in[2];
    const float* Wx1 = (const float*)d_in[3];
    const float* bx1 = (const float*)d_in[4];
    const float* bh1 = (const float*)d_in[6];
    const float* Wx2 = (const float*)d_in[7];
    const float* bx2 = (const float*)d_in[8];
    const float* bh2 = (const float*)d_in[10];
    const float* Wl  = (const float*)d_in[11];
    const float* bl  = (const float*)d_in[12];
    float* out = (float*)d_out;

    float* ws     = (float*)d_ws;
    float* dis    = ws;                         // 50048 floats
    int*   bh     = (int*)(ws + 50048);         // NCH*NBP ints
    int*   tot    = bh + NCH * NBP;             // NBP ints
    int*   off_bk = tot + NBP;                  // NBP ints
    int2*  edges  = (int2*)(off_bk + NBP);      // PADE int2 (padded buckets)
    float* T1     = (float*)(edges + PADE);     // NN*32 floats each
    float* T2     = T1 + NN * 32;
    float* T3     = T2 + NN * 32;
    float* T4     = T3 + NN * 32;
    float* hb     = T4 + NN * 32;
    int*   deg_g  = (int*)T1;  // 256*QTR ints (T1+T2 region, dead before spmm)

    k_deg  <<<256, 1024, 0, stream>>>(ei, ew, deg_g);
    k_dis2 <<<NB, 256, 0, stream>>>(deg_g, dis);
    k_bhist<<<NCH, 1024, 0, stream>>>(ei, bh);
    k_btot <<<7, 256, 0, stream>>>(bh, tot);
    k_bscan1<<<1, 1024, 0, stream>>>(tot, off_bk);
    k_bcur <<<7, 256, 0, stream>>>(bh, off_bk);
    k_pad  <<<NBK, 128, 0, stream>>>(off_bk, tot, edges);
    k_cperm<<<NCH, 1024, 0, stream>>>(ei, ew, dis, bh, edges);

    // ---- cell 1: v = x ----
    k_spmm<<<NBK, 256, 0, stream>>>(off_bk, edges, x,  nullptr, T1, 1.f);
    k_spmm<<<NBK, 256, 0, stream>>>(off_bk, edges, T1, x,       T2, 2.f);
    k_spmm<<<NBK, 256, 0, stream>>>(off_bk, edges, T2, T1,      T3, 2.f);
    k_spmm<<<NBK, 256, 0, stream>>>(off_bk, edges, T3, T2,      T4, 2.f);
    k_epi1<<<GE, 256, 0, stream>>>(x, T1, T2, T3, T4, Wx1, bx1, bh1, hb);

    // ---- cell 2: v = hb ----
    k_spmm<<<NBK, 256, 0, stream>>>(off_bk, edges, hb, nullptr, T1, 1.f);
    k_spmm<<<NBK, 256, 0, stream>>>(off_bk, edges, T1, hb,      T2, 2.f);
    k_spmm<<<NBK, 256, 0, stream>>>(off_bk, edges, T2, T1,      T3, 2.f);
    k_spmm<<<NBK, 256, 0, stream>>>(off_bk, edges, T3, T2,      T4, 2.f);
    k_epi2<<<GE, 256, 0, stream>>>(hb, T1, T2, T3, T4, Wx2, bx2, bh2, Wl, bl, out);
}

// Round 14
// 364.758 us; speedup vs baseline: 1.7811x; 1.0319x over previous
//
#include <hip/hip_runtime.h>
#include <math.h>

#define NN 50000
#define NE 1600000
#define KORD 5
#define NB 196          // ceil(NN/256)
#define QTR 12500       // node quarter (k_deg)
#define GE 782          // epi grid: ceil(NN/64)
#define MT 64           // epi node tile
#define NBK 1563        // ceil(NN/32) destination buckets (32 nodes each)
#define NBP 1600        // padded bucket stride
#define NCH 256         // chunks for bucket kernels (fills all CUs)
#define ECH (NE / NCH)  // 6250
#define EC4 (NE / 64)   // 25000 (k_deg chunks)
#define PADE 1800192    // edge buffer capacity (NE + NBK*128, rounded)

#define SCALE_W 2097152.0f          // 2^21 spmm fixed point
#define INV_SCALE_W (1.0f / 2097152.0f)
#define SCALE_D 4194304.0f          // 2^22 degree fixed point
#define INV_SCALE_D (1.0f / 4194304.0f)

typedef _Float16 half8 __attribute__((ext_vector_type(8)));
typedef _Float16 half4v __attribute__((ext_vector_type(4)));
typedef float float4v __attribute__((ext_vector_type(4)));

// ---------------- deg: LDS int-fixed-point weighted row histogram ----------
__global__ __launch_bounds__(1024) void k_deg(const int* __restrict__ ei,
                                              const float* __restrict__ ew,
                                              int* __restrict__ deg_g) {
    __shared__ int h[QTR];   // 50 KB
    int q = blockIdx.x >> 6, ch = blockIdx.x & 63;
    for (int i = threadIdx.x; i < QTR; i += 1024) h[i] = 0;
    __syncthreads();
    int base = ch * EC4, lo = q * QTR;
    for (int e = base + threadIdx.x; e < base + EC4; e += 1024) {
        int li = ei[e] - lo;
        if ((unsigned)li < (unsigned)QTR)
            atomicAdd(&h[li], __float2int_rn(ew[e] * SCALE_D));  // ds_add_u32
    }
    __syncthreads();
    int* outp = deg_g + blockIdx.x * QTR;
    for (int i = threadIdx.x; i < QTR; i += 1024) outp[i] = h[i];
}

__global__ __launch_bounds__(256) void k_dis2(const int* __restrict__ deg_g,
                                              float* __restrict__ dis) {
    int n = blockIdx.x * 256 + threadIdx.x;
    if (n >= NN) return;
    int q = n / QTR, i = n % QTR;
    const int* p = deg_g + (q * 64) * QTR + i;
    int s = 0;
#pragma unroll
    for (int c = 0; c < 64; c++) s += p[c * QTR];
    float d = (float)s * INV_SCALE_D;
    dis[n] = s > 0 ? rsqrtf(fmaxf(d, 1e-30f)) : 0.f;
}

// ---------------- bucket histogram: bh[ch][b] ----------
__global__ __launch_bounds__(1024) void k_bhist(const int* __restrict__ ei,
                                                int* __restrict__ bh) {
    __shared__ int hist[NBK];
    int ch = blockIdx.x;
    for (int i = threadIdx.x; i < NBK; i += 1024) hist[i] = 0;
    __syncthreads();
    const int* cols = ei + NE;
    int base = ch * ECH;
    for (int e = base + threadIdx.x; e < base + ECH; e += 1024)
        atomicAdd(&hist[cols[e] >> 5], 1);
    __syncthreads();
    int* outp = bh + ch * NBP;
    for (int b = threadIdx.x; b < NBK; b += 1024) outp[b] = hist[b];
}

__global__ __launch_bounds__(256) void k_btot(const int* __restrict__ bh,
                                              int* __restrict__ tot) {
    int b = blockIdx.x * 256 + threadIdx.x;
    if (b >= NBP) return;
    int s = 0;
    if (b < NBK) {
#pragma unroll 8
        for (int ch = 0; ch < NCH; ch++) s += bh[ch * NBP + b];
    }
    tot[b] = s;
}

// one block: pair-compressed exclusive scan of PADDED totals -> off_bk
__global__ __launch_bounds__(1024) void k_bscan1(const int* __restrict__ tot,
                                                 int* __restrict__ off_bk) {
    __shared__ int s[1024];
    int t = threadIdx.x;
    int a0 = (2 * t < NBP) ? tot[2 * t] : 0;
    int a1 = (2 * t + 1 < NBP) ? tot[2 * t + 1] : 0;
    int p0 = (a0 + 127) & ~127;
    int p1 = (a1 + 127) & ~127;
    s[t] = p0 + p1;
    __syncthreads();
    for (int d = 1; d < 1024; d <<= 1) {
        int u = (t >= d) ? s[t - d] : 0;
        __syncthreads();
        s[t] += u;
        __syncthreads();
    }
    int excl = (t == 0) ? 0 : s[t - 1];
    if (2 * t < NBK) off_bk[2 * t] = excl;
    if (2 * t + 1 < NBK) off_bk[2 * t + 1] = excl + p0;
    if (t == 1023) off_bk[NBK] = s[1023];
}

__global__ __launch_bounds__(256) void k_bcur(int* __restrict__ bh,
                                              const int* __restrict__ off_bk) {
    int b = blockIdx.x * 256 + threadIdx.x;
    if (b >= NBK) return;
    int run = off_bk[b];
    for (int ch = 0; ch < NCH; ch++) {
        int v = bh[ch * NBP + b];
        bh[ch * NBP + b] = run;
        run += v;
    }
}

// fill pad region of each bucket with zero-weight sentinel edges
__global__ __launch_bounds__(128) void k_pad(const int* __restrict__ off_bk,
                                             const int* __restrict__ tot,
                                             int2* __restrict__ edges) {
    int b = blockIdx.x;
    int start = off_bk[b] + tot[b];
    int end = off_bk[b + 1];
    for (int i = start + threadIdx.x; i < end; i += 128)
        edges[i] = make_int2(0, 0);   // r=0, c_local=0, w=0.0f
}

// coarse permute: record = (r | local_c<<16, weight-bits)
__global__ __launch_bounds__(1024) void k_cperm(const int* __restrict__ ei,
                                                const float* __restrict__ ew,
                                                const float* __restrict__ dis,
                                                const int* __restrict__ bh,
                                                int2* __restrict__ edges) {
    __shared__ int cur[NBK];
    int ch = blockIdx.x;
    const int* cp = bh + ch * NBP;
    for (int b = threadIdx.x; b < NBK; b += 1024) cur[b] = cp[b];
    __syncthreads();
    int base = ch * ECH;
    for (int e = base + threadIdx.x; e < base + ECH; e += 1024) {
        int r = ei[e], c = ei[NE + e];
        float w = -dis[r] * ew[e] * dis[c];
        int pos = atomicAdd(&cur[c >> 5], 1);   // ds_add_u32, native
        int packed = (int)((unsigned)r | ((unsigned)(c & 31) << 16));
        edges[pos] = make_int2(packed, __float_as_int(w));
    }
}

// ---------------- spmm: 32-node buckets, 3-stage pipeline -------------------
// per iteration: load records(k+1) || gather(k) || ds-add(k-1).
#define SPMM_DS(C0, W0, G0, C1, W1, G1, C2, W2, G2, C3, W3, G3)      \
    {                                                                 \
        int* a0 = &acc[C0][sub * 4];                                  \
        int* a1 = &acc[C1][sub * 4];                                  \
        int* a2 = &acc[C2][sub * 4];                                  \
        int* a3 = &acc[C3][sub * 4];                                  \
        atomicAdd(a0 + 0, __float2int_rn(W0 * G0.x));                 \
        atomicAdd(a0 + 1, __float2int_rn(W0 * G0.y));                 \
        atomicAdd(a0 + 2, __float2int_rn(W0 * G0.z));                 \
        atomicAdd(a0 + 3, __float2int_rn(W0 * G0.w));                 \
        atomicAdd(a1 + 0, __float2int_rn(W1 * G1.x));                 \
        atomicAdd(a1 + 1, __float2int_rn(W1 * G1.y));                 \
        atomicAdd(a1 + 2, __float2int_rn(W1 * G1.z));                 \
        atomicAdd(a1 + 3, __float2int_rn(W1 * G1.w));                 \
        atomicAdd(a2 + 0, __float2int_rn(W2 * G2.x));                 \
        atomicAdd(a2 + 1, __float2int_rn(W2 * G2.y));                 \
        atomicAdd(a2 + 2, __float2int_rn(W2 * G2.z));                 \
        atomicAdd(a2 + 3, __float2int_rn(W2 * G2.w));                 \
        atomicAdd(a3 + 0, __float2int_rn(W3 * G3.x));                 \
        atomicAdd(a3 + 1, __float2int_rn(W3 * G3.y));                 \
        atomicAdd(a3 + 2, __float2int_rn(W3 * G3.z));                 \
        atomicAdd(a3 + 3, __float2int_rn(W3 * G3.w));                 \
    }

__global__ __launch_bounds__(256) void k_spmm(const int* __restrict__ off_bk,
                                              const int2* __restrict__ edges,
                                              const float* __restrict__ vin,
                                              const float* __restrict__ prev,
                                              float* __restrict__ vout,
                                              float scale) {
    __shared__ int acc[32][33];
    int b = blockIdx.x;
    for (int i = threadIdx.x; i < 32 * 33; i += 256) (&acc[0][0])[i] = 0;
    __syncthreads();
    int e0 = off_bk[b], e1 = off_bk[b + 1];
    int group = threadIdx.x >> 3, sub = threadIdx.x & 7;
    const float4* vin4 = (const float4*)vin;
    int i = e0 + group;
    if (i < e1) {
        // records of the batch to gather this iteration
        int2 R0 = edges[i], R1 = edges[i + 32], R2 = edges[i + 64], R3 = edges[i + 96];
        float4 G0, G1, G2, G3;        // gathered batch awaiting DS
        int C0 = 0, C1 = 0, C2 = 0, C3 = 0;
        float W0 = 0.f, W1 = 0.f, W2 = 0.f, W3 = 0.f;
        bool haveG = false;
        while (true) {
            int ni = i + 128;
            bool moreR = ni < e1;
            int2 N0, N1, N2, N3;
            if (moreR) {                           // stage 1: next records
                N0 = edges[ni]; N1 = edges[ni + 32];
                N2 = edges[ni + 64]; N3 = edges[ni + 96];
            }
            // stage 2: gather current records (independent of stage 1)
            float4 g0 = vin4[((unsigned)R0.x & 0xffffu) * 8 + sub];
            float4 g1 = vin4[((unsigned)R1.x & 0xffffu) * 8 + sub];
            float4 g2 = vin4[((unsigned)R2.x & 0xffffu) * 8 + sub];
            float4 g3 = vin4[((unsigned)R3.x & 0xffffu) * 8 + sub];
            // stage 3: DS the previous batch (its gathers had a full iter in flight)
            if (haveG) SPMM_DS(C0, W0, G0, C1, W1, G1, C2, W2, G2, C3, W3, G3);
            C0 = (unsigned)R0.x >> 16; C1 = (unsigned)R1.x >> 16;
            C2 = (unsigned)R2.x >> 16; C3 = (unsigned)R3.x >> 16;
            W0 = __int_as_float(R0.y) * SCALE_W;
            W1 = __int_as_float(R1.y) * SCALE_W;
            W2 = __int_as_float(R2.y) * SCALE_W;
            W3 = __int_as_float(R3.y) * SCALE_W;
            G0 = g0; G1 = g1; G2 = g2; G3 = g3;
            haveG = true;
            if (!moreR) break;
            R0 = N0; R1 = N1; R2 = N2; R3 = N3;
            i = ni;
        }
        SPMM_DS(C0, W0, G0, C1, W1, G1, C2, W2, G2, C3, W3, G3);
    }
    __syncthreads();
    float sf = scale * INV_SCALE_W;
    int base = b << 5;
    int nl = threadIdx.x >> 3, s4 = threadIdx.x & 7;
    int n = base + nl;
    if (n < NN) {
        const int* a = &acc[nl][s4 * 4];
        float4 o;
        if (prev) {
            float4 p = ((const float4*)prev)[n * 8 + s4];
            o = make_float4(fmaf(sf, (float)a[0], -p.x),
                            fmaf(sf, (float)a[1], -p.y),
                            fmaf(sf, (float)a[2], -p.z),
                            fmaf(sf, (float)a[3], -p.w));
        } else {
            o = make_float4(sf * (float)a[0], sf * (float)a[1],
                            sf * (float)a[2], sf * (float)a[3]);
        }
        ((float4*)vout)[n * 8 + s4] = o;
    }
}

// ---------------- epi1: MFMA GEMM (64 nodes x 64 outs x K=160) + GRU --------
__global__ __launch_bounds__(256) void k_epi1(
    const float* __restrict__ x, const float* __restrict__ t1,
    const float* __restrict__ t2, const float* __restrict__ t3,
    const float* __restrict__ t4, const float* __restrict__ Wx1,
    const float* __restrict__ bx1, const float* __restrict__ bh1,
    float* __restrict__ h) {
    __shared__ _Float16 T[5][MT][40];   // 25.6 KB
    __shared__ _Float16 Wt[64][168];    // 21.5 KB, [n][k]
    int n0 = blockIdx.x * MT;
    const float* bufs[5] = {x, t1, t2, t3, t4};
#pragma unroll
    for (int b = 0; b < 5; b++) {
        for (int idx = threadIdx.x; idx < MT * 8; idx += 256) {
            int r = idx >> 3, c4 = idx & 7;
            int rr = n0 + r; if (rr >= NN) rr = NN - 1;
            float4 v = *(const float4*)(bufs[b] + rr * 32 + c4 * 4);
            *(half4v*)&T[b][r][c4 * 4] =
                (half4v){(_Float16)v.x, (_Float16)v.y, (_Float16)v.z, (_Float16)v.w};
        }
    }
    const float* Wz = Wx1;
    const float* Wh = Wx1 + 2 * KORD * 32 * 32;
    for (int idx = threadIdx.x; idx < 160 * 64; idx += 256) {
        int k = idx >> 6, n = idx & 63;
        int b = k >> 5, i = k & 31;
        float w = (n < 32) ? Wz[b * 1024 + i * 32 + n]
                           : Wh[b * 1024 + i * 32 + (n - 32)];
        Wt[n][k] = (_Float16)w;
    }
    __syncthreads();
    int wave = threadIdx.x >> 6;
    int lane = threadIdx.x & 63;
    int lo = lane & 15, quad = lane >> 4;
    float4v acc[4];
#pragma unroll
    for (int t = 0; t < 4; t++) acc[t] = (float4v){0.f, 0.f, 0.f, 0.f};
#pragma unroll
    for (int b = 0; b < 5; b++) {
        half8 a = *(half8*)&T[b][wave * 16 + lo][quad * 8];
#pragma unroll
        for (int t = 0; t < 4; t++) {
            half8 bf = *(half8*)&Wt[t * 16 + lo][b * 32 + quad * 8];
            acc[t] = __builtin_amdgcn_mfma_f32_16x16x32_f16(a, bf, acc[t], 0, 0, 0);
        }
    }
    int nd_base = n0 + wave * 16 + quad * 4;
#pragma unroll
    for (int t = 0; t < 2; t++) {
        int j = t * 16 + lo;
        float bz = bx1[j] + bh1[j];
        float bhb = bx1[64 + j] + bh1[64 + j];
#pragma unroll
        for (int reg = 0; reg < 4; reg++) {
            int nd = nd_base + reg;
            if (nd < NN) {
                float zz = acc[t][reg] + bz;
                float hh = acc[t + 2][reg] + bhb;
                float z = 1.f / (1.f + __expf(-zz));
                float tt = __expf(-2.f * fabsf(hh));
                float ht = copysignf((1.f - tt) / (1.f + tt), hh);
                h[nd * 32 + j] = fmaxf((1.f - z) * ht, 0.f);
            }
        }
    }
}

// ---------------- epi2: MFMA GEMM (64 x 32 x 160) + GRU + final linear ------
__global__ __launch_bounds__(256) void k_epi2(
    const float* __restrict__ hin, const float* __restrict__ t1,
    const float* __restrict__ t2, const float* __restrict__ t3,
    const float* __restrict__ t4, const float* __restrict__ Wx2,
    const float* __restrict__ bx2, const float* __restrict__ bh2,
    const float* __restrict__ Wl, const float* __restrict__ bl,
    float* __restrict__ out) {
    __shared__ _Float16 T[5][MT][40];   // 25.6 KB
    __shared__ _Float16 Wt[32][168];    // 10.8 KB
    __shared__ float H2[MT][17];
    int n0 = blockIdx.x * MT;
    const float* bufs[5] = {hin, t1, t2, t3, t4};
#pragma unroll
    for (int b = 0; b < 5; b++) {
        for (int idx = threadIdx.x; idx < MT * 8; idx += 256) {
            int r = idx >> 3, c4 = idx & 7;
            int rr = n0 + r; if (rr >= NN) rr = NN - 1;
            float4 v = *(const float4*)(bufs[b] + rr * 32 + c4 * 4);
            *(half4v*)&T[b][r][c4 * 4] =
                (half4v){(_Float16)v.x, (_Float16)v.y, (_Float16)v.z, (_Float16)v.w};
        }
    }
    const float* Wz = Wx2;
    const float* Wh = Wx2 + 2 * KORD * 32 * 16;
    for (int idx = threadIdx.x; idx < 160 * 32; idx += 256) {
        int k = idx >> 5, n = idx & 31;
        int b = k >> 5, i = k & 31;
        float w = (n < 16) ? Wz[b * 512 + i * 16 + n]
                           : Wh[b * 512 + i * 16 + (n - 16)];
        Wt[n][k] = (_Float16)w;
    }
    __syncthreads();
    int wave = threadIdx.x >> 6;
    int lane = threadIdx.x & 63;
    int lo = lane & 15, quad = lane >> 4;
    float4v acc[2];
    acc[0] = (float4v){0.f, 0.f, 0.f, 0.f};
    acc[1] = (float4v){0.f, 0.f, 0.f, 0.f};
#pragma unroll
    for (int b = 0; b < 5; b++) {
        half8 a = *(half8*)&T[b][wave * 16 + lo][quad * 8];
#pragma unroll
        for (int t = 0; t < 2; t++) {
            half8 bf = *(half8*)&Wt[t * 16 + lo][b * 32 + quad * 8];
            acc[t] = __builtin_amdgcn_mfma_f32_16x16x32_f16(a, bf, acc[t], 0, 0, 0);
        }
    }
    {
        int j = lo;
        float bz = bx2[j] + bh2[j];
        float bhb = bx2[32 + j] + bh2[32 + j];
        int ndl_base = wave * 16 + quad * 4;
#pragma unroll
        for (int reg = 0; reg < 4; reg++) {
            float zz = acc[0][reg] + bz;
            float hh = acc[1][reg] + bhb;
            float z = 1.f / (1.f + __expf(-zz));
            float tt = __expf(-2.f * fabsf(hh));
            float ht = copysignf((1.f - tt) / (1.f + tt), hh);
            H2[ndl_base + reg][j] = fmaxf((1.f - z) * ht, 0.f);
        }
    }
    __syncthreads();
    for (int idx = threadIdx.x; idx < MT * 12; idx += 256) {
        int n = idx / 12, p = idx % 12;
        int gn = n0 + n;
        if (gn < NN) {
            float o = bl[p];
#pragma unroll
            for (int jj = 0; jj < 16; jj++) o = fmaf(H2[n][jj], Wl[p * 16 + jj], o);
            out[gn * 12 + p] = o;
        }
    }
}

// ---------------- launch ----------------

extern "C" void kernel_launch(void* const* d_in, const int* in_sizes, int n_in,
                              void* d_out, int out_size, void* d_ws, size_t ws_size,
                              hipStream_t stream) {
    const float* x   = (const float*)d_in[0];
    const int*   ei  = (const int*)d_in[1];
    const float* ew  = (const float*)d_in[2];
    const float* Wx1 = (const float*)d_in[3];
    const float* bx1 = (const float*)d_in[4];
    const float* bh1 = (const float*)d_in[6];
    const float* Wx2 = (const float*)d_in[7];
    const float* bx2 = (const float*)d_in[8];
    const float* bh2 = (const float*)d_in[10];
    const float* Wl  = (const float*)d_in[11];
    const float* bl  = (const float*)d_in[12];
    float* out = (float*)d_out;

    float* ws     = (float*)d_ws;
    float* dis    = ws;                         // 50048 floats
    int*   bh     = (int*)(ws + 50048);         // NCH*NBP = 409600 ints
    int*   tot    = bh + NCH * NBP;             // NBP ints
    int*   off_bk = tot + NBP;                  // NBP ints
    int2*  edges  = (int2*)(off_bk + NBP);      // PADE int2 (padded buckets)
    float* T1     = (float*)(edges + PADE);     // NN*32 floats each
    float* T2     = T1 + NN * 32;
    float* T3     = T2 + NN * 32;
    float* T4     = T3 + NN * 32;
    float* hb     = T4 + NN * 32;
    int*   deg_g  = (int*)T1;  // 256*QTR ints (T1+T2 region, dead before spmm)

    k_deg  <<<256, 1024, 0, stream>>>(ei, ew, deg_g);
    k_dis2 <<<NB, 256, 0, stream>>>(deg_g, dis);
    k_bhist<<<NCH, 1024, 0, stream>>>(ei, bh);
    k_btot <<<7, 256, 0, stream>>>(bh, tot);
    k_bscan1<<<1, 1024, 0, stream>>>(tot, off_bk);
    k_bcur <<<7, 256, 0, stream>>>(bh, off_bk);
    k_pad  <<<NBK, 128, 0, stream>>>(off_bk, tot, edges);
    k_cperm<<<NCH, 1024, 0, stream>>>(ei, ew, dis, bh, edges);

    // ---- cell 1: v = x ----
    k_spmm<<<NBK, 256, 0, stream>>>(off_bk, edges, x,  nullptr, T1, 1.f);
    k_spmm<<<NBK, 256, 0, stream>>>(off_bk, edges, T1, x,       T2, 2.f);
    k_spmm<<<NBK, 256, 0, stream>>>(off_bk, edges, T2, T1,      T3, 2.f);
    k_spmm<<<NBK, 256, 0, stream>>>(off_bk, edges, T3, T2,      T4, 2.f);
    k_epi1<<<GE, 256, 0, stream>>>(x, T1, T2, T3, T4, Wx1, bx1, bh1, hb);

    // ---- cell 2: v = hb ----
    k_spmm<<<NBK, 256, 0, stream>>>(off_bk, edges, hb, nullptr, T1, 1.f);
    k_spmm<<<NBK, 256, 0, stream>>>(off_bk, edges, T1, hb,      T2, 2.f);
    k_spmm<<<NBK, 256, 0, stream>>>(off_bk, edges, T2, T1,      T3, 2.f);
    k_spmm<<<NBK, 256, 0, stream>>>(off_bk, edges, T3, T2,      T4, 2.f);
    k_epi2<<<GE, 256, 0, stream>>>(hb, T1, T2, T3, T4, Wx2, bx2, bh2, Wl, bl, out);
}